// Round 1
// baseline (342.273 us; speedup 1.0000x reference)
//
#include <hip/hip_runtime.h>
#include <stdint.h>

// Problem constants (B,S,D fixed by harness)
constexpr int S = 1024;
constexpr int D = 1024;
constexpr int NB = 8;

typedef __bf16 bf16x8 __attribute__((ext_vector_type(8)));
typedef float floatx4 __attribute__((ext_vector_type(4)));

#define AS1 __attribute__((address_space(1)))
#define AS3 __attribute__((address_space(3)))

__device__ __forceinline__ unsigned short f2bf(float f) {
  unsigned u = __builtin_bit_cast(unsigned, f);
  u += 0x7fffu + ((u >> 16) & 1u);   // RNE
  return (unsigned short)(u >> 16);
}

__device__ __forceinline__ void gload16(const void* g, void* l) {
  // async global->LDS, 16B per lane; LDS dest = wave-uniform base + lane*16
  __builtin_amdgcn_global_load_lds((const AS1 unsigned int*)g, (AS3 unsigned int*)l, 16, 0, 0);
}

// ---------------- cast fp32 -> bf16 (contiguous) ----------------
__global__ __launch_bounds__(256) void cast_bf16_kernel(const float4* __restrict__ in,
                                                        ushort4* __restrict__ out, int n4) {
  int i = blockIdx.x * 256 + threadIdx.x;
  if (i >= n4) return;
  float4 v = in[i];
  ushort4 o;
  o.x = f2bf(v.x); o.y = f2bf(v.y); o.z = f2bf(v.z); o.w = f2bf(v.w);
  out[i] = o;
}

// ---------------- W (KxN fp32) -> Wt (NxK bf16) ----------------
__global__ __launch_bounds__(256) void transpose_w_kernel(const float* __restrict__ W,
                                                          unsigned short* __restrict__ Wt) {
  __shared__ float tile[32][33];
  int bx = blockIdx.x * 32;  // n block
  int by = blockIdx.y * 32;  // k block
  int x = threadIdx.x & 31;
  int y0 = threadIdx.x >> 5;  // 0..7
  for (int i = 0; i < 4; ++i) {
    int y = y0 + i * 8;
    tile[y][x] = W[(by + y) * D + bx + x];
  }
  __syncthreads();
  for (int i = 0; i < 4; ++i) {
    int y = y0 + i * 8;
    Wt[(long long)(bx + y) * D + by + x] = f2bf(tile[x][y]);
  }
}

// ---------------- NT GEMM: C = A (MxK, row) * Bt (NxK, row)^T ----------------
// MODE 0: C bf16 row-major [m][n] (ld=D), + bias[n]
// MODE 1: C bf16 transposed-per-batch: addr=(m>>10)*S*D + n*S + (m&1023), + bias[n]  (Vm_t)
// MODE 2: C fp32 row-major batched: z*strideC + m*S + n, * alpha                     (scores)
// MODE 3: C fp32 permuted attention output: z*strideC + (n>>6)*S*64 + m*64 + (n&63)  (ctx)
template <int MODE>
__global__ __launch_bounds__(256) void gemm_nt_kernel(
    const unsigned short* __restrict__ A, int lda, long long strideA,
    const unsigned short* __restrict__ Bt, int ldb, long long strideB,
    void* __restrict__ Cv, long long strideC,
    const float* __restrict__ bias, float alpha, int K) {
  __shared__ __align__(16) unsigned short As[128 * 32];
  __shared__ __align__(16) unsigned short Bs[128 * 32];
  const int tid = threadIdx.x;
  const int lane = tid & 63;
  const int w = tid >> 6;                 // wave 0..3
  const int z = blockIdx.z;
  const long long m0 = (long long)blockIdx.y * 128;
  const long long n0 = (long long)blockIdx.x * 128;
  A += (long long)z * strideA;
  Bt += (long long)z * strideB;

  // staging: 512 slots of 16B for each of As/Bs; slot idx -> row idx>>2, chunk idx&3
  const int idx0 = tid, idx1 = tid + 256;
  const unsigned short* aG0 = A + (m0 + (idx0 >> 2)) * lda + (idx0 & 3) * 8;
  const unsigned short* aG1 = A + (m0 + (idx1 >> 2)) * lda + (idx1 & 3) * 8;
  const unsigned short* bG0 = Bt + (n0 + (idx0 >> 2)) * ldb + (idx0 & 3) * 8;
  const unsigned short* bG1 = Bt + (n0 + (idx1 >> 2)) * ldb + (idx1 & 3) * 8;
  unsigned short* aL0 = As + w * 512;         // byte off w*1024 (wave-uniform)
  unsigned short* aL1 = As + w * 512 + 2048;  // +4096B
  unsigned short* bL0 = Bs + w * 512;
  unsigned short* bL1 = Bs + w * 512 + 2048;

  floatx4 zero4 = {0.f, 0.f, 0.f, 0.f};
  floatx4 acc[4][4];
  for (int i = 0; i < 4; ++i)
    for (int j = 0; j < 4; ++j) acc[i][j] = zero4;

  const int r15 = lane & 15;
  const int quad = lane >> 4;
  const int wm = (w >> 1) * 64;
  const int wn = (w & 1) * 64;

  for (int k0 = 0; k0 < K; k0 += 32) {
    gload16(aG0 + k0, aL0);
    gload16(aG1 + k0, aL1);
    gload16(bG0 + k0, bL0);
    gload16(bG1 + k0, bL1);
    __syncthreads();  // drains vmcnt -> LDS tiles complete
    bf16x8 af[4], bfr[4];
    for (int t = 0; t < 4; ++t) {
      af[t] = *reinterpret_cast<const bf16x8*>(As + (wm + t * 16 + r15) * 32 + quad * 8);
      bfr[t] = *reinterpret_cast<const bf16x8*>(Bs + (wn + t * 16 + r15) * 32 + quad * 8);
    }
    for (int mt = 0; mt < 4; ++mt)
      for (int nt = 0; nt < 4; ++nt)
        acc[mt][nt] =
            __builtin_amdgcn_mfma_f32_16x16x32_bf16(af[mt], bfr[nt], acc[mt][nt], 0, 0, 0);
    __syncthreads();  // protect LDS from next iteration's staging
  }

  // epilogue: C/D layout col=lane&15, row=(lane>>4)*4+reg  [verified m89/m91]
  for (int mt = 0; mt < 4; ++mt) {
    for (int nt = 0; nt < 4; ++nt) {
      const long long mrow = m0 + wm + mt * 16 + quad * 4;
      const long long ncol = n0 + wn + nt * 16 + r15;
      const float bv = bias ? bias[ncol] : 0.f;
      floatx4 v = acc[mt][nt];
      for (int e = 0; e < 4; ++e) {
        float val = v[e] * alpha + bv;
        long long m = mrow + e;
        if constexpr (MODE == 0) {
          ((unsigned short*)Cv)[m * D + ncol] = f2bf(val);
        } else if constexpr (MODE == 1) {
          ((unsigned short*)Cv)[(m >> 10) * (long long)(S * D) + ncol * S + (m & 1023)] = f2bf(val);
        } else if constexpr (MODE == 2) {
          ((float*)Cv)[(long long)z * strideC + m * S + ncol] = val;
        } else {
          ((float*)Cv)[(long long)z * strideC + (ncol >> 6) * (long long)(S * 64) + m * 64 +
                       (ncol & 63)] = val;
        }
      }
    }
  }
}

// ---------------- masked softmax over rows; bf16 probs in-place (row stride 2048) --------
__global__ __launch_bounds__(256) void softmax_kernel(const float* scores,
                                                      const float* __restrict__ mask,
                                                      unsigned short* probs) {
  const long long row = blockIdx.x;  // b*S + q
  const float* s = scores + row * S;
  const float* mk = mask + row * S;
  unsigned short* p = probs + row * 2048;
  const int tid = threadIdx.x;
  const int lane = tid & 63, w = tid >> 6;
  float v[4];
  float mx = -3.4e38f;
  for (int i = 0; i < 4; ++i) {
    int j = tid + i * 256;
    float val = s[j] + (1.0f - mk[j]) * -1e9f;
    v[i] = val;
    mx = fmaxf(mx, val);
  }
  for (int off = 32; off; off >>= 1) mx = fmaxf(mx, __shfl_xor(mx, off, 64));
  __shared__ float redm[4], reds[4];
  if (lane == 0) redm[w] = mx;
  __syncthreads();  // also orders all scores-reads before the in-place probs writes below
  mx = fmaxf(fmaxf(redm[0], redm[1]), fmaxf(redm[2], redm[3]));
  float sum = 0.f;
  for (int i = 0; i < 4; ++i) {
    v[i] = __expf(v[i] - mx);
    sum += v[i];
  }
  for (int off = 32; off; off >>= 1) sum += __shfl_xor(sum, off, 64);
  if (lane == 0) reds[w] = sum;
  __syncthreads();
  sum = reds[0] + reds[1] + reds[2] + reds[3];
  float inv = 1.0f / sum;
  for (int i = 0; i < 4; ++i) {
    int j = tid + i * 256;
    p[j] = f2bf(v[i] * inv);
  }
}

extern "C" void kernel_launch(void* const* d_in, const int* in_sizes, int n_in, void* d_out,
                              int out_size, void* d_ws, size_t ws_size, hipStream_t stream) {
  const float* hs = (const float*)d_in[0];
  const float* rhs = (const float*)d_in[1];
  const float* mask = (const float*)d_in[2];
  const float* Wq = (const float*)d_in[3];
  const float* bq = (const float*)d_in[4];
  const float* Wk = (const float*)d_in[5];
  const float* bk = (const float*)d_in[6];
  const float* Wv = (const float*)d_in[7];
  const float* bv = (const float*)d_in[8];
  float* out = (float*)d_out;
  char* ws = (char*)d_ws;
  const size_t MB = 1ull << 20;
  // layout (86 MB total): Wt x3 | hs_bf16 | rhs_bf16 | Qm | Km | Vm_t ; scores(32MB fp32)
  // overlays hs_bf16+rhs_bf16 (dead after QKV GEMMs); probs bf16 in-place in scores rows.
  unsigned short* Wqt = (unsigned short*)(ws + 0 * MB);
  unsigned short* Wkt = (unsigned short*)(ws + 2 * MB);
  unsigned short* Wvt = (unsigned short*)(ws + 4 * MB);
  unsigned short* hsb = (unsigned short*)(ws + 6 * MB);
  unsigned short* rhsb = (unsigned short*)(ws + 22 * MB);
  unsigned short* Qm = (unsigned short*)(ws + 38 * MB);
  unsigned short* Km = (unsigned short*)(ws + 54 * MB);
  unsigned short* Vmt = (unsigned short*)(ws + 70 * MB);
  float* scores = (float*)(ws + 6 * MB);
  unsigned short* probs = (unsigned short*)scores;

  const int n4 = NB * S * D / 4;  // 2M float4s
  cast_bf16_kernel<<<n4 / 256, 256, 0, stream>>>((const float4*)hs, (ushort4*)hsb, n4);
  cast_bf16_kernel<<<n4 / 256, 256, 0, stream>>>((const float4*)rhs, (ushort4*)rhsb, n4);
  dim3 tg(32, 32);
  transpose_w_kernel<<<tg, 256, 0, stream>>>(Wq, Wqt);
  transpose_w_kernel<<<tg, 256, 0, stream>>>(Wk, Wkt);
  transpose_w_kernel<<<tg, 256, 0, stream>>>(Wv, Wvt);

  // QKV projections (M=8192)
  gemm_nt_kernel<0><<<dim3(8, 64, 1), 256, 0, stream>>>(hsb, D, 0, Wqt, D, 0, Qm, 0, bq, 1.f, D);
  gemm_nt_kernel<0><<<dim3(8, 64, 1), 256, 0, stream>>>(rhsb, D, 0, Wkt, D, 0, Km, 0, bk, 1.f, D);
  gemm_nt_kernel<1><<<dim3(8, 64, 1), 256, 0, stream>>>(rhsb, D, 0, Wvt, D, 0, Vmt, 0, bv, 1.f, D);
  // scores[b] = Qm[b] * Km[b]^T / 8   (batched, fp32 out)
  gemm_nt_kernel<2><<<dim3(8, 8, NB), 256, 0, stream>>>(Qm, D, (long long)S * D, Km, D,
                                                        (long long)S * D, scores, (long long)S * S,
                                                        nullptr, 0.125f, D);
  softmax_kernel<<<NB * S, 256, 0, stream>>>(scores, mask, probs);
  // ctx[b] = probs[b] * Vm_t[b]^T, permuted fp32 store into d_out
  gemm_nt_kernel<3><<<dim3(8, 8, NB), 256, 0, stream>>>(probs, 2048, (long long)S * 2048, Vmt, D,
                                                        (long long)S * D, out, (long long)S * D,
                                                        nullptr, 1.f, D);
}

// Round 2
// 316.516 us; speedup vs baseline: 1.0814x; 1.0814x over previous
//
#include <hip/hip_runtime.h>
#include <stdint.h>

constexpr int S = 1024;
constexpr int D = 1024;
constexpr int NB = 8;

typedef __bf16 bf16x8 __attribute__((ext_vector_type(8)));
typedef float floatx4 __attribute__((ext_vector_type(4)));

#define AS1 __attribute__((address_space(1)))
#define AS3 __attribute__((address_space(3)))

__device__ __forceinline__ unsigned short f2bf(float f) {
  unsigned u = __builtin_bit_cast(unsigned, f);
  u += 0x7fffu + ((u >> 16) & 1u);  // RNE
  return (unsigned short)(u >> 16);
}

__device__ __forceinline__ void gload16(const void* g, void* l) {
  __builtin_amdgcn_global_load_lds((const AS1 unsigned int*)g, (AS3 unsigned int*)l, 16, 0, 0);
}

// ---------------- cast fp32 -> bf16, both inputs in one dispatch ----------------
__global__ __launch_bounds__(256) void cast2_bf16_kernel(const float4* __restrict__ a,
                                                         const float4* __restrict__ b,
                                                         ushort4* __restrict__ oa,
                                                         ushort4* __restrict__ ob, int n4) {
  int i = blockIdx.x * 256 + threadIdx.x;
  const float4* src;
  ushort4* dst;
  int j;
  if (i < n4) {
    src = a; dst = oa; j = i;
  } else {
    src = b; dst = ob; j = i - n4;
  }
  float4 v = src[j];
  ushort4 o;
  o.x = f2bf(v.x); o.y = f2bf(v.y); o.z = f2bf(v.z); o.w = f2bf(v.w);
  dst[j] = o;
}

// ---------------- 3x W (KxN fp32) -> Wcat ((3N)xK bf16) ----------------
__global__ __launch_bounds__(256) void transpose_w3_kernel(const float* __restrict__ Wq,
                                                           const float* __restrict__ Wk,
                                                           const float* __restrict__ Wv,
                                                           unsigned short* __restrict__ Wcat) {
  __shared__ float tile[32][33];
  const float* W = (blockIdx.z == 0) ? Wq : (blockIdx.z == 1) ? Wk : Wv;
  unsigned short* Wt = Wcat + (long long)blockIdx.z * D * D;
  int bx = blockIdx.x * 32;  // n block
  int by = blockIdx.y * 32;  // k block
  int x = threadIdx.x & 31;
  int y0 = threadIdx.x >> 5;
  for (int i = 0; i < 4; ++i) {
    int y = y0 + i * 8;
    tile[y][x] = W[(by + y) * D + bx + x];
  }
  __syncthreads();
  for (int i = 0; i < 4; ++i) {
    int y = y0 + i * 8;
    Wt[(long long)(bx + y) * D + by + x] = f2bf(tile[x][y]);
  }
}

// ---------------- fused QKV GEMM: M=8192, N=3072 (seg 0..2 = Q,K,V) ----------------
__global__ __launch_bounds__(256) void gemm_qkv_kernel(
    const unsigned short* __restrict__ hsb, const unsigned short* __restrict__ rhsb,
    const unsigned short* __restrict__ Wcat, unsigned short* __restrict__ Qm,
    unsigned short* __restrict__ Km, unsigned short* __restrict__ Vmt,
    const float* __restrict__ bq, const float* __restrict__ bk, const float* __restrict__ bv) {
  __shared__ __align__(16) unsigned short As[128 * 32];
  __shared__ __align__(16) unsigned short Bs[128 * 32];
  const int tid = threadIdx.x;
  const int lane = tid & 63;
  const int w = tid >> 6;
  const long long n0g = (long long)blockIdx.x * 128;  // global col 0..3071
  const int seg = (int)(n0g >> 10);                   // 0=Q 1=K 2=V (block-uniform)
  const long long m0 = (long long)blockIdx.y * 128;
  const unsigned short* A = (seg == 0) ? hsb : rhsb;
  const unsigned short* Bt = Wcat + n0g * D;  // 128 rows of [n][k]
  const float* bias = (seg == 0) ? bq : (seg == 1) ? bk : bv;

  const int idx0 = tid, idx1 = tid + 256;
  const unsigned short* aG0 = A + (m0 + (idx0 >> 2)) * D + (idx0 & 3) * 8;
  const unsigned short* aG1 = A + (m0 + (idx1 >> 2)) * D + (idx1 & 3) * 8;
  const unsigned short* bG0 = Bt + (long long)(idx0 >> 2) * D + (idx0 & 3) * 8;
  const unsigned short* bG1 = Bt + (long long)(idx1 >> 2) * D + (idx1 & 3) * 8;
  unsigned short* aL0 = As + w * 512;
  unsigned short* aL1 = As + w * 512 + 2048;
  unsigned short* bL0 = Bs + w * 512;
  unsigned short* bL1 = Bs + w * 512 + 2048;

  floatx4 zero4 = {0.f, 0.f, 0.f, 0.f};
  floatx4 acc[4][4];
  for (int i = 0; i < 4; ++i)
    for (int j = 0; j < 4; ++j) acc[i][j] = zero4;

  const int r15 = lane & 15;
  const int quad = lane >> 4;
  const int wm = (w >> 1) * 64;
  const int wn = (w & 1) * 64;

  for (int k0 = 0; k0 < D; k0 += 32) {
    gload16(aG0 + k0, aL0);
    gload16(aG1 + k0, aL1);
    gload16(bG0 + k0, bL0);
    gload16(bG1 + k0, bL1);
    __syncthreads();
    bf16x8 af[4], bfr[4];
    for (int t = 0; t < 4; ++t) {
      af[t] = *reinterpret_cast<const bf16x8*>(As + (wm + t * 16 + r15) * 32 + quad * 8);
      bfr[t] = *reinterpret_cast<const bf16x8*>(Bs + (wn + t * 16 + r15) * 32 + quad * 8);
    }
    for (int mt = 0; mt < 4; ++mt)
      for (int nt = 0; nt < 4; ++nt)
        acc[mt][nt] =
            __builtin_amdgcn_mfma_f32_16x16x32_bf16(af[mt], bfr[nt], acc[mt][nt], 0, 0, 0);
    __syncthreads();
  }

  const long long nloc0 = n0g & 1023;  // col within segment
  for (int mt = 0; mt < 4; ++mt) {
    for (int nt = 0; nt < 4; ++nt) {
      const long long mrow = m0 + wm + mt * 16 + quad * 4;
      const long long nc = nloc0 + wn + nt * 16 + r15;
      const float bval = bias[nc];
      floatx4 v = acc[mt][nt];
      for (int e = 0; e < 4; ++e) {
        float val = v[e] + bval;
        long long m = mrow + e;
        if (seg == 0) {
          Qm[m * D + nc] = f2bf(val);
        } else if (seg == 1) {
          Km[m * D + nc] = f2bf(val);
        } else {
          Vmt[(m >> 10) * (long long)(S * D) + nc * S + (m & 1023)] = f2bf(val);
        }
      }
    }
  }
}

// ---------------- NT GEMM for scores / ctx ----------------
// MODE 2: C fp32 batched row-major: z*strideC + m*S + n, * alpha         (scores)
// MODE 3: C fp32 permuted: z*strideC + (n>>6)*S*64 + m*64 + (n&63)       (ctx)
template <int MODE>
__global__ __launch_bounds__(256) void gemm_nt_kernel(
    const unsigned short* __restrict__ A, int lda, long long strideA,
    const unsigned short* __restrict__ Bt, int ldb, long long strideB, float* __restrict__ C,
    long long strideC, float alpha, int K) {
  __shared__ __align__(16) unsigned short As[128 * 32];
  __shared__ __align__(16) unsigned short Bs[128 * 32];
  const int tid = threadIdx.x;
  const int lane = tid & 63;
  const int w = tid >> 6;
  const int z = blockIdx.z;
  const long long m0 = (long long)blockIdx.y * 128;
  const long long n0 = (long long)blockIdx.x * 128;
  A += (long long)z * strideA;
  Bt += (long long)z * strideB;

  const int idx0 = tid, idx1 = tid + 256;
  const unsigned short* aG0 = A + (m0 + (idx0 >> 2)) * lda + (idx0 & 3) * 8;
  const unsigned short* aG1 = A + (m0 + (idx1 >> 2)) * lda + (idx1 & 3) * 8;
  const unsigned short* bG0 = Bt + (n0 + (idx0 >> 2)) * ldb + (idx0 & 3) * 8;
  const unsigned short* bG1 = Bt + (n0 + (idx1 >> 2)) * ldb + (idx1 & 3) * 8;
  unsigned short* aL0 = As + w * 512;
  unsigned short* aL1 = As + w * 512 + 2048;
  unsigned short* bL0 = Bs + w * 512;
  unsigned short* bL1 = Bs + w * 512 + 2048;

  floatx4 zero4 = {0.f, 0.f, 0.f, 0.f};
  floatx4 acc[4][4];
  for (int i = 0; i < 4; ++i)
    for (int j = 0; j < 4; ++j) acc[i][j] = zero4;

  const int r15 = lane & 15;
  const int quad = lane >> 4;
  const int wm = (w >> 1) * 64;
  const int wn = (w & 1) * 64;

  for (int k0 = 0; k0 < K; k0 += 32) {
    gload16(aG0 + k0, aL0);
    gload16(aG1 + k0, aL1);
    gload16(bG0 + k0, bL0);
    gload16(bG1 + k0, bL1);
    __syncthreads();
    bf16x8 af[4], bfr[4];
    for (int t = 0; t < 4; ++t) {
      af[t] = *reinterpret_cast<const bf16x8*>(As + (wm + t * 16 + r15) * 32 + quad * 8);
      bfr[t] = *reinterpret_cast<const bf16x8*>(Bs + (wn + t * 16 + r15) * 32 + quad * 8);
    }
    for (int mt = 0; mt < 4; ++mt)
      for (int nt = 0; nt < 4; ++nt)
        acc[mt][nt] =
            __builtin_amdgcn_mfma_f32_16x16x32_bf16(af[mt], bfr[nt], acc[mt][nt], 0, 0, 0);
    __syncthreads();
  }

  for (int mt = 0; mt < 4; ++mt) {
    for (int nt = 0; nt < 4; ++nt) {
      const long long mrow = m0 + wm + mt * 16 + quad * 4;
      const long long ncol = n0 + wn + nt * 16 + r15;
      floatx4 v = acc[mt][nt];
      for (int e = 0; e < 4; ++e) {
        float val = v[e] * alpha;
        long long m = mrow + e;
        if constexpr (MODE == 2) {
          C[(long long)z * strideC + m * S + ncol] = val;
        } else {
          C[(long long)z * strideC + (ncol >> 6) * (long long)(S * 64) + m * 64 + (ncol & 63)] =
              val;
        }
      }
    }
  }
}

// ---------------- masked softmax; bf16 probs in-place (row stride 2048 elems) ----------
__global__ __launch_bounds__(256) void softmax_kernel(const float* scores,
                                                      const float* __restrict__ mask,
                                                      unsigned short* probs) {
  const long long row = blockIdx.x;  // b*S + q
  const float4* s4 = (const float4*)(scores + row * S);
  const float4* m4 = (const float4*)(mask + row * S);
  ushort4* p4 = (ushort4*)(probs + row * 2048);
  const int tid = threadIdx.x;
  const int lane = tid & 63, w = tid >> 6;
  float4 sv = s4[tid];
  float4 mv = m4[tid];
  float v[4] = {sv.x + (1.0f - mv.x) * -1e9f, sv.y + (1.0f - mv.y) * -1e9f,
                sv.z + (1.0f - mv.z) * -1e9f, sv.w + (1.0f - mv.w) * -1e9f};
  float mx = fmaxf(fmaxf(v[0], v[1]), fmaxf(v[2], v[3]));
  for (int off = 32; off; off >>= 1) mx = fmaxf(mx, __shfl_xor(mx, off, 64));
  __shared__ float redm[4], reds[4];
  if (lane == 0) redm[w] = mx;
  __syncthreads();  // orders all scores-reads before the in-place probs writes too
  mx = fmaxf(fmaxf(redm[0], redm[1]), fmaxf(redm[2], redm[3]));
  float sum = 0.f;
  for (int i = 0; i < 4; ++i) {
    v[i] = __expf(v[i] - mx);
    sum += v[i];
  }
  for (int off = 32; off; off >>= 1) sum += __shfl_xor(sum, off, 64);
  if (lane == 0) reds[w] = sum;
  __syncthreads();
  sum = reds[0] + reds[1] + reds[2] + reds[3];
  float inv = 1.0f / sum;
  ushort4 o;
  o.x = f2bf(v[0] * inv);
  o.y = f2bf(v[1] * inv);
  o.z = f2bf(v[2] * inv);
  o.w = f2bf(v[3] * inv);
  p4[tid] = o;
}

extern "C" void kernel_launch(void* const* d_in, const int* in_sizes, int n_in, void* d_out,
                              int out_size, void* d_ws, size_t ws_size, hipStream_t stream) {
  const float* hs = (const float*)d_in[0];
  const float* rhs = (const float*)d_in[1];
  const float* mask = (const float*)d_in[2];
  const float* Wq = (const float*)d_in[3];
  const float* bq = (const float*)d_in[4];
  const float* Wk = (const float*)d_in[5];
  const float* bk = (const float*)d_in[6];
  const float* Wv = (const float*)d_in[7];
  const float* bv = (const float*)d_in[8];
  float* out = (float*)d_out;
  char* ws = (char*)d_ws;
  const size_t MB = 1ull << 20;
  // layout: Wcat(6MB) | hs_bf16(16) | rhs_bf16(16) | Qm(16) | Km(16) | Vm_t(16) = 86 MB
  // scores (32MB fp32) overlays hs_bf16+rhs_bf16 (dead after QKV GEMM); probs bf16 in-place.
  unsigned short* Wcat = (unsigned short*)(ws + 0 * MB);
  unsigned short* hsb = (unsigned short*)(ws + 6 * MB);
  unsigned short* rhsb = (unsigned short*)(ws + 22 * MB);
  unsigned short* Qm = (unsigned short*)(ws + 38 * MB);
  unsigned short* Km = (unsigned short*)(ws + 54 * MB);
  unsigned short* Vmt = (unsigned short*)(ws + 70 * MB);
  float* scores = (float*)(ws + 6 * MB);
  unsigned short* probs = (unsigned short*)scores;

  const int n4 = NB * S * D / 4;  // 2M float4 per input
  cast2_bf16_kernel<<<2 * n4 / 256, 256, 0, stream>>>((const float4*)hs, (const float4*)rhs,
                                                      (ushort4*)hsb, (ushort4*)rhsb, n4);
  transpose_w3_kernel<<<dim3(32, 32, 3), 256, 0, stream>>>(Wq, Wk, Wv, Wcat);

  // fused QKV projections: M=8192, N=3072, 1536 blocks (6 blocks/CU)
  gemm_qkv_kernel<<<dim3(24, 64), 256, 0, stream>>>(hsb, rhsb, Wcat, Qm, Km, Vmt, bq, bk, bv);

  // scores[b] = Qm[b] * Km[b]^T / 8   (batched, fp32 out)
  gemm_nt_kernel<2><<<dim3(8, 8, NB), 256, 0, stream>>>(Qm, D, (long long)S * D, Km, D,
                                                        (long long)S * D, scores,
                                                        (long long)S * S, 0.125f, D);
  softmax_kernel<<<NB * S, 256, 0, stream>>>(scores, mask, probs);
  // ctx[b] = probs[b] * Vm_t[b]^T, permuted fp32 store into d_out
  gemm_nt_kernel<3><<<dim3(8, 8, NB), 256, 0, stream>>>(probs, 2048, (long long)S * 2048, Vmt, D,
                                                        (long long)S * D, out, (long long)S * D,
                                                        1.f, D);
}

// Round 3
// 304.202 us; speedup vs baseline: 1.1251x; 1.0405x over previous
//
#include <hip/hip_runtime.h>
#include <stdint.h>

constexpr int S = 1024;
constexpr int D = 1024;
constexpr int NB = 8;

typedef __bf16 bf16x8 __attribute__((ext_vector_type(8)));
typedef float floatx4 __attribute__((ext_vector_type(4)));

#define AS1 __attribute__((address_space(1)))
#define AS3 __attribute__((address_space(3)))

__device__ __forceinline__ unsigned short f2bf(float f) {
  unsigned u = __builtin_bit_cast(unsigned, f);
  u += 0x7fffu + ((u >> 16) & 1u);  // RNE
  return (unsigned short)(u >> 16);
}

__device__ __forceinline__ void gload16(const void* g, void* l) {
  __builtin_amdgcn_global_load_lds((const AS1 unsigned int*)g, (AS3 unsigned int*)l, 16, 0, 0);
}

// ---------------- prep: cast both inputs to bf16 + transpose 3 weights ----------------
// blocks [0,16384): cast; blocks [16384,19456): transpose (z = weight, 32x32 tiles)
__global__ __launch_bounds__(256) void prep_kernel(const float4* __restrict__ hs4,
                                                   const float4* __restrict__ rhs4,
                                                   ushort4* __restrict__ hsb4,
                                                   ushort4* __restrict__ rhsb4, int n4,
                                                   const float* __restrict__ Wq,
                                                   const float* __restrict__ Wk,
                                                   const float* __restrict__ Wv,
                                                   unsigned short* __restrict__ Wcat) {
  __shared__ float tile[32][33];
  const int bid = blockIdx.x;
  if (bid < 16384) {
    int i = bid * 256 + threadIdx.x;
    const float4* src;
    ushort4* dst;
    int j;
    if (i < n4) {
      src = hs4; dst = hsb4; j = i;
    } else {
      src = rhs4; dst = rhsb4; j = i - n4;
    }
    float4 v = src[j];
    ushort4 o;
    o.x = f2bf(v.x); o.y = f2bf(v.y); o.z = f2bf(v.z); o.w = f2bf(v.w);
    dst[j] = o;
  } else {
    const int t = bid - 16384;  // 0..3071
    const int z = t >> 10;
    const int r = t & 1023;
    const float* W = (z == 0) ? Wq : (z == 1) ? Wk : Wv;
    unsigned short* Wt = Wcat + (long long)z * D * D;
    const int bx = (r & 31) * 32;  // n block
    const int by = (r >> 5) * 32;  // k block
    const int x = threadIdx.x & 31;
    const int y0 = threadIdx.x >> 5;
    for (int i = 0; i < 4; ++i) {
      int y = y0 + i * 8;
      tile[y][x] = W[(by + y) * D + bx + x];
    }
    __syncthreads();
    for (int i = 0; i < 4; ++i) {
      int y = y0 + i * 8;
      Wt[(long long)(bx + y) * D + by + x] = f2bf(tile[x][y]);
    }
  }
}

// ============ shared GEMM core pieces: 128x128 tile, BK=64, XOR bank swizzle ============
// LDS: As/Bs 128 rows x 64 bf16 (8 chunks of 16B per row). Chunk swizzle: LDS chunk c holds
// global chunk c ^ (row&7) -> every 16-lane ds_read_b128 phase covers all 32 banks 2-way.

// ---------------- fused QKV GEMM: M=8192, N=3072 (1536 blocks, XCD-compact n) ----------
__global__ __launch_bounds__(256) void gemm_qkv_kernel(
    const unsigned short* __restrict__ hsb, const unsigned short* __restrict__ rhsb,
    const unsigned short* __restrict__ Wcat, unsigned short* __restrict__ Qm,
    unsigned short* __restrict__ Km, unsigned short* __restrict__ Vmt,
    const float* __restrict__ bq, const float* __restrict__ bk, const float* __restrict__ bv) {
  __shared__ __align__(16) unsigned short As[128 * 64];
  __shared__ __align__(16) unsigned short Bs[128 * 64];
  const int tid = threadIdx.x;
  const int lane = tid & 63;
  const int w = tid >> 6;
  // XCD-compact: bid&7 -> XCD; each XCD owns 3 n-tiles (768KB of Wcat, L2-resident)
  const int bid = blockIdx.x;
  const int local = bid >> 3;
  const int n_tile = (bid & 7) * 3 + (local % 3);  // 0..23
  const long long m0 = (long long)(local / 3) * 128;
  const long long n0g = (long long)n_tile * 128;
  const int seg = n_tile >> 3;  // 0=Q 1=K 2=V
  const unsigned short* A = (seg == 0) ? hsb : rhsb;
  const unsigned short* Bt = Wcat + n0g * D;
  const float* bias = (seg == 0) ? bq : (seg == 1) ? bk : bv;

  const unsigned short* aG[4];
  const unsigned short* bG[4];
  for (int j = 0; j < 4; ++j) {
    int idx = tid + j * 256;
    int row = idx >> 3;
    int cg = (idx & 7) ^ (row & 7);
    aG[j] = A + (m0 + row) * D + cg * 8;
    bG[j] = Bt + (long long)row * D + cg * 8;
  }

  floatx4 zero4 = {0.f, 0.f, 0.f, 0.f};
  floatx4 acc[4][4];
  for (int i = 0; i < 4; ++i)
    for (int j = 0; j < 4; ++j) acc[i][j] = zero4;

  const int r15 = lane & 15;
  const int quad = lane >> 4;
  const int wm = (w >> 1) * 64;
  const int wn = (w & 1) * 64;

  for (int k0 = 0; k0 < D; k0 += 64) {
    for (int j = 0; j < 4; ++j) gload16(aG[j] + k0, As + j * 2048 + w * 512);
    for (int j = 0; j < 4; ++j) gload16(bG[j] + k0, Bs + j * 2048 + w * 512);
    __syncthreads();
    for (int kk = 0; kk < 2; ++kk) {
      const int ca = ((kk << 2) | quad) ^ (r15 & 7);
      bf16x8 af[4], bfr[4];
      for (int t = 0; t < 4; ++t) {
        af[t] = *reinterpret_cast<const bf16x8*>(As + (wm + t * 16 + r15) * 64 + ca * 8);
        bfr[t] = *reinterpret_cast<const bf16x8*>(Bs + (wn + t * 16 + r15) * 64 + ca * 8);
      }
      for (int mt = 0; mt < 4; ++mt)
        for (int nt = 0; nt < 4; ++nt)
          acc[mt][nt] =
              __builtin_amdgcn_mfma_f32_16x16x32_bf16(af[mt], bfr[nt], acc[mt][nt], 0, 0, 0);
    }
    __syncthreads();
  }

  const long long nloc0 = n0g & 1023;
  for (int mt = 0; mt < 4; ++mt) {
    for (int nt = 0; nt < 4; ++nt) {
      const long long mrow = m0 + wm + mt * 16 + quad * 4;
      const long long nc = nloc0 + wn + nt * 16 + r15;
      const float bval = bias[nc];
      floatx4 v = acc[mt][nt];
      for (int e = 0; e < 4; ++e) {
        float val = v[e] + bval;
        long long m = mrow + e;
        if (seg == 0) {
          Qm[m * D + nc] = f2bf(val);
        } else if (seg == 1) {
          Km[m * D + nc] = f2bf(val);
        } else {
          Vmt[(m >> 10) * (long long)(S * D) + nc * S + (m & 1023)] = f2bf(val);
        }
      }
    }
  }
}

// ---------------- batched NT GEMM, batch = bid&7 (XCD-local) ----------------
// MODE 2: C fp32 row-major: z*strideC + m*S + n, * alpha        (scores)
// MODE 3: C fp32 permuted: z*strideC + (n>>6)*S*64 + m*64 + (n&63)  (ctx)
template <int MODE>
__global__ __launch_bounds__(256) void gemm_nt_kernel(
    const unsigned short* __restrict__ A, int lda, long long strideA,
    const unsigned short* __restrict__ Bt, int ldb, long long strideB, float* __restrict__ C,
    long long strideC, float alpha, int K) {
  __shared__ __align__(16) unsigned short As[128 * 64];
  __shared__ __align__(16) unsigned short Bs[128 * 64];
  const int tid = threadIdx.x;
  const int lane = tid & 63;
  const int w = tid >> 6;
  const int bid = blockIdx.x;
  const int z = bid & 7;        // batch == XCD
  const int local = bid >> 3;   // 0..63
  const long long m0 = (long long)(local & 7) * 128;
  const long long n0 = (long long)(local >> 3) * 128;
  A += (long long)z * strideA;
  Bt += (long long)z * strideB;

  const unsigned short* aG[4];
  const unsigned short* bG[4];
  for (int j = 0; j < 4; ++j) {
    int idx = tid + j * 256;
    int row = idx >> 3;
    int cg = (idx & 7) ^ (row & 7);
    aG[j] = A + (m0 + row) * lda + cg * 8;
    bG[j] = Bt + (n0 + row) * ldb + cg * 8;
  }

  floatx4 zero4 = {0.f, 0.f, 0.f, 0.f};
  floatx4 acc[4][4];
  for (int i = 0; i < 4; ++i)
    for (int j = 0; j < 4; ++j) acc[i][j] = zero4;

  const int r15 = lane & 15;
  const int quad = lane >> 4;
  const int wm = (w >> 1) * 64;
  const int wn = (w & 1) * 64;

  for (int k0 = 0; k0 < K; k0 += 64) {
    for (int j = 0; j < 4; ++j) gload16(aG[j] + k0, As + j * 2048 + w * 512);
    for (int j = 0; j < 4; ++j) gload16(bG[j] + k0, Bs + j * 2048 + w * 512);
    __syncthreads();
    for (int kk = 0; kk < 2; ++kk) {
      const int ca = ((kk << 2) | quad) ^ (r15 & 7);
      bf16x8 af[4], bfr[4];
      for (int t = 0; t < 4; ++t) {
        af[t] = *reinterpret_cast<const bf16x8*>(As + (wm + t * 16 + r15) * 64 + ca * 8);
        bfr[t] = *reinterpret_cast<const bf16x8*>(Bs + (wn + t * 16 + r15) * 64 + ca * 8);
      }
      for (int mt = 0; mt < 4; ++mt)
        for (int nt = 0; nt < 4; ++nt)
          acc[mt][nt] =
              __builtin_amdgcn_mfma_f32_16x16x32_bf16(af[mt], bfr[nt], acc[mt][nt], 0, 0, 0);
    }
    __syncthreads();
  }

  for (int mt = 0; mt < 4; ++mt) {
    for (int nt = 0; nt < 4; ++nt) {
      const long long mrow = m0 + wm + mt * 16 + quad * 4;
      const long long ncol = n0 + wn + nt * 16 + r15;
      floatx4 v = acc[mt][nt];
      for (int e = 0; e < 4; ++e) {
        float val = v[e] * alpha;
        long long m = mrow + e;
        if constexpr (MODE == 2) {
          C[(long long)z * strideC + m * S + ncol] = val;
        } else {
          C[(long long)z * strideC + (ncol >> 6) * (long long)(S * 64) + m * 64 + (ncol & 63)] =
              val;
        }
      }
    }
  }
}

// ---------------- masked softmax; bf16 probs in-place (row stride 2048 elems) ----------
__global__ __launch_bounds__(256) void softmax_kernel(const float* scores,
                                                      const float* __restrict__ mask,
                                                      unsigned short* probs) {
  const int bid = blockIdx.x;
  const long long row = (long long)(bid & 7) * 1024 + (bid >> 3);  // batch == XCD
  const float4* s4 = (const float4*)(scores + row * S);
  const float4* m4 = (const float4*)(mask + row * S);
  ushort4* p4 = (ushort4*)(probs + row * 2048);
  const int tid = threadIdx.x;
  const int lane = tid & 63, w = tid >> 6;
  float4 sv = s4[tid];
  float4 mv = m4[tid];
  float v[4] = {sv.x + (1.0f - mv.x) * -1e9f, sv.y + (1.0f - mv.y) * -1e9f,
                sv.z + (1.0f - mv.z) * -1e9f, sv.w + (1.0f - mv.w) * -1e9f};
  float mx = fmaxf(fmaxf(v[0], v[1]), fmaxf(v[2], v[3]));
  for (int off = 32; off; off >>= 1) mx = fmaxf(mx, __shfl_xor(mx, off, 64));
  __shared__ float redm[4], reds[4];
  if (lane == 0) redm[w] = mx;
  __syncthreads();  // orders all scores-reads before the in-place probs writes too
  mx = fmaxf(fmaxf(redm[0], redm[1]), fmaxf(redm[2], redm[3]));
  float sum = 0.f;
  for (int i = 0; i < 4; ++i) {
    v[i] = __expf(v[i] - mx);
    sum += v[i];
  }
  for (int off = 32; off; off >>= 1) sum += __shfl_xor(sum, off, 64);
  if (lane == 0) reds[w] = sum;
  __syncthreads();
  sum = reds[0] + reds[1] + reds[2] + reds[3];
  float inv = 1.0f / sum;
  ushort4 o;
  o.x = f2bf(v[0] * inv);
  o.y = f2bf(v[1] * inv);
  o.z = f2bf(v[2] * inv);
  o.w = f2bf(v[3] * inv);
  p4[tid] = o;
}

extern "C" void kernel_launch(void* const* d_in, const int* in_sizes, int n_in, void* d_out,
                              int out_size, void* d_ws, size_t ws_size, hipStream_t stream) {
  const float* hs = (const float*)d_in[0];
  const float* rhs = (const float*)d_in[1];
  const float* mask = (const float*)d_in[2];
  const float* Wq = (const float*)d_in[3];
  const float* bq = (const float*)d_in[4];
  const float* Wk = (const float*)d_in[5];
  const float* bk = (const float*)d_in[6];
  const float* Wv = (const float*)d_in[7];
  const float* bv = (const float*)d_in[8];
  float* out = (float*)d_out;
  char* ws = (char*)d_ws;
  const size_t MB = 1ull << 20;
  // layout: Wcat(6MB) | hs_bf16(16) | rhs_bf16(16) | Qm(16) | Km(16) | Vm_t(16) = 86 MB
  // scores (32MB fp32) overlays hs_bf16+rhs_bf16 (dead after QKV GEMM); probs bf16 in-place.
  unsigned short* Wcat = (unsigned short*)(ws + 0 * MB);
  unsigned short* hsb = (unsigned short*)(ws + 6 * MB);
  unsigned short* rhsb = (unsigned short*)(ws + 22 * MB);
  unsigned short* Qm = (unsigned short*)(ws + 38 * MB);
  unsigned short* Km = (unsigned short*)(ws + 54 * MB);
  unsigned short* Vmt = (unsigned short*)(ws + 70 * MB);
  float* scores = (float*)(ws + 6 * MB);
  unsigned short* probs = (unsigned short*)scores;

  const int n4 = NB * S * D / 4;  // 2M float4 per input
  prep_kernel<<<16384 + 3072, 256, 0, stream>>>((const float4*)hs, (const float4*)rhs,
                                                (ushort4*)hsb, (ushort4*)rhsb, n4, Wq, Wk, Wv,
                                                Wcat);

  // fused QKV projections: M=8192, N=3072, 1536 blocks, XCD-compact n
  gemm_qkv_kernel<<<1536, 256, 0, stream>>>(hsb, rhsb, Wcat, Qm, Km, Vmt, bq, bk, bv);

  // scores[b] = Qm[b] * Km[b]^T / 8   (batched, fp32 out, batch==XCD)
  gemm_nt_kernel<2><<<512, 256, 0, stream>>>(Qm, D, (long long)S * D, Km, D, (long long)S * D,
                                             scores, (long long)S * S, 0.125f, D);
  softmax_kernel<<<NB * S, 256, 0, stream>>>(scores, mask, probs);
  // ctx[b] = probs[b] * Vm_t[b]^T, permuted fp32 store into d_out
  gemm_nt_kernel<3><<<512, 256, 0, stream>>>(probs, 2048, (long long)S * 2048, Vmt, D,
                                             (long long)S * D, out, (long long)S * D, 1.f, D);
}